// Round 1
// baseline (3921.220 us; speedup 1.0000x reference)
//
#include <hip/hip_runtime.h>

// Problem constants
constexpr int Bz = 512;   // batch
constexpr int Tz = 256;   // seq len
constexpr int Hz = 256;   // hidden
constexpr int Pz = 14;    // predict dim
constexpr int GB = 16;    // batch groups
constexpr int GS = 16;    // hidden slices per group
constexpr int BT = 32;    // batch per group (512/16)
constexpr int HU = 16;    // hidden units per slice (256/16)
constexpr int KP = 264;   // padded K stride in bf16 elems (256 + 8 -> kills 16-way LDS bank conflicts)

typedef short s8v __attribute__((ext_vector_type(8)));
typedef float f4v __attribute__((ext_vector_type(4)));

__device__ __forceinline__ short f2bf(float f) {
  unsigned u = __float_as_uint(f);
  u = (u + 0x7fffu + ((u >> 16) & 1u)) >> 16;   // RNE
  return (short)u;
}
__device__ __forceinline__ float bf2f(short s) {
  return __uint_as_float(((unsigned)(unsigned short)s) << 16);
}
__device__ __forceinline__ float sigm(float v) { return 1.0f / (1.0f + __expf(-v)); }
__device__ __forceinline__ float tanh_f(float v) { return 1.0f - 2.0f / (__expf(2.0f * v) + 1.0f); }

// 256 blocks (16 batch-groups x 16 hidden-slices), 256 threads, 1 block/CU (LDS ~149KB).
// Per batch-group: 16 blocks sync via a device-scope monotonic counter barrier.
// Pipeline: at step s, layer0 computes t=s, layer1 computes t=s-1. 257 steps.
__global__ void __launch_bounds__(256, 1)
lstm2(const float* __restrict__ x,
      const float* __restrict__ w_ih0, const float* __restrict__ w_hh0,
      const float* __restrict__ b_ih0, const float* __restrict__ b_hh0,
      const float* __restrict__ w_ih1, const float* __restrict__ w_hh1,
      const float* __restrict__ b_ih1, const float* __restrict__ b_hh1,
      const float* __restrict__ w_lin, const float* __restrict__ b_lin,
      float* __restrict__ out,
      unsigned* __restrict__ bars,
      short* __restrict__ h0g, short* __restrict__ h1g)
{
  const int blk  = blockIdx.x;
  const int g    = blk >> 4;      // batch group
  const int sl   = blk & 15;      // hidden slice
  const int tid  = threadIdx.x;
  const int wave = tid >> 6;      // 4 waves: wave == gate type (i,f,g,o)
  const int lane = tid & 63;
  const int q    = lane >> 4;     // quad within wave
  const int l15  = lane & 15;
  const int gbase = g * BT;

  extern __shared__ char smem_raw[];
  short* W0   = (short*)smem_raw;          // [64][KP] W_hh0 slice (bf16)
  short* W1i  = W0  + 64 * KP;             // [64][KP] W_ih1 slice
  short* W1h  = W1i + 64 * KP;             // [64][KP] W_hh1 slice
  short* h0s  = W1h + 64 * KP;             // [32][KP] staged h0[t-1] (full H)
  short* h1s  = h0s + 32 * KP;             // [32][KP] staged h1[t-2] (full H)
  float* gbuf   = (float*)(h1s + 32 * KP); // [4][32][17] activated gates
  float* c0     = gbuf + 4 * 32 * 17;      // [32][17] cell state layer0 (slice-local)
  float* c1     = c0 + 32 * 17;            // [32][17] cell state layer1
  float* xs     = c1 + 32 * 17;            // [32] x[b][t]
  float* wih0s  = xs + 32;                 // [64] w_ih0 rows
  float* bias0s = wih0s + 64;              // [64] b_ih0+b_hh0
  float* bias1s = bias0s + 64;             // [64] b_ih1+b_hh1

  // ---- one-time: load weight slices into LDS (fp32 -> bf16) ----
  for (int i = tid; i < 64 * 256; i += 256) {
    int n = i >> 8, k = i & 255;
    int grow = (n >> 4) * Hz + sl * HU + (n & 15);  // gate*256 + global hidden unit
    W0 [n * KP + k] = f2bf(w_hh0[grow * Hz + k]);
    W1i[n * KP + k] = f2bf(w_ih1[grow * Hz + k]);
    W1h[n * KP + k] = f2bf(w_hh1[grow * Hz + k]);
  }
  if (tid < 64) {
    int n = tid;
    int grow = (n >> 4) * Hz + sl * HU + (n & 15);
    wih0s[n]  = w_ih0[grow];
    bias0s[n] = b_ih0[grow] + b_hh0[grow];
    bias1s[n] = b_ih1[grow] + b_hh1[grow];
  }
  for (int i = tid; i < 32 * 17; i += 256) { c0[i] = 0.0f; c1[i] = 0.0f; }
  __syncthreads();

  unsigned* bar = bars + (g << 6);   // 256B-separated counter per group

  for (int s = 0; s <= Tz; ++s) {
    // ---- stage h0[s-1] (read buf (s-1)&1 == (s+1)&1) and h1[s-2] (buf s&1) ----
    {
      const s8v* h0src = (const s8v*)(h0g + (size_t)(((s + 1) & 1) * Bz + gbase) * Hz);
      const s8v* h1src = (const s8v*)(h1g + (size_t)(((s    ) & 1) * Bz + gbase) * Hz);
      for (int i = tid; i < BT * Hz / 8; i += 256) {   // 1024 chunks of 16B
        int b = i >> 5, ch = i & 31;
        *(s8v*)(h0s + b * KP + ch * 8) = h0src[b * 32 + ch];
        *(s8v*)(h1s + b * KP + ch * 8) = h1src[b * 32 + ch];
      }
      if (tid < BT && s < Tz) xs[tid] = x[(gbase + tid) * Tz + s];
    }
    __syncthreads();

    // ---- layer 0, time t=s: gates = pre0 + h0_prev @ W0^T ----
    if (s < Tz) {
      f4v acc0 = {0.f, 0.f, 0.f, 0.f}, acc1 = {0.f, 0.f, 0.f, 0.f};
      const short* Wr = W0  + (wave * 16 + l15) * KP + q * 8;  // B-frag: row n, k chunk
      const short* Ar = h0s + l15 * KP + q * 8;                // A-frag: row m, k chunk
      #pragma unroll
      for (int kt = 0; kt < 8; ++kt) {
        s8v bf = *(const s8v*)(Wr + kt * 32);
        s8v a0 = *(const s8v*)(Ar + kt * 32);
        s8v a1 = *(const s8v*)(Ar + 16 * KP + kt * 32);
        acc0 = __builtin_amdgcn_mfma_f32_16x16x32_bf16(a0, bf, acc0, 0, 0, 0);
        acc1 = __builtin_amdgcn_mfma_f32_16x16x32_bf16(a1, bf, acc1, 0, 0, 0);
      }
      float wih = wih0s[wave * 16 + l15];
      float bia = bias0s[wave * 16 + l15];
      #pragma unroll
      for (int r = 0; r < 4; ++r) {
        int b0 = q * 4 + r;                        // D: row(m)=q*4+r, col(n)=l15
        float v0 = acc0[r] + xs[b0]      * wih + bia;
        float v1 = acc1[r] + xs[b0 + 16] * wih + bia;
        if (wave == 2) { v0 = tanh_f(v0); v1 = tanh_f(v1); }
        else           { v0 = sigm(v0);   v1 = sigm(v1);   }
        gbuf[(wave * 32 + b0     ) * 17 + l15] = v0;
        gbuf[(wave * 32 + b0 + 16) * 17 + l15] = v1;
      }
    }
    __syncthreads();
    if (s < Tz) {
      short* dst = h0g + (size_t)((s & 1) * Bz + gbase) * Hz + sl * HU;
      for (int i = tid; i < BT * HU; i += 256) {
        int b = i >> 4, u = i & 15;
        float iv = gbuf[(     b) * 17 + u];
        float fv = gbuf[(32 + b) * 17 + u];
        float gv = gbuf[(64 + b) * 17 + u];
        float ov = gbuf[(96 + b) * 17 + u];
        float c = fv * c0[b * 17 + u] + iv * gv;
        c0[b * 17 + u] = c;
        dst[b * Hz + u] = f2bf(ov * tanh_f(c));
      }
    }
    __syncthreads();   // gbuf reuse fence before layer1 epilogue

    // ---- layer 1, time t=s-1: gates = bias1 + h0[s-1] @ W1i^T + h1[s-2] @ W1h^T ----
    if (s >= 1) {
      f4v acc0 = {0.f, 0.f, 0.f, 0.f}, acc1 = {0.f, 0.f, 0.f, 0.f};
      const short* Wi = W1i + (wave * 16 + l15) * KP + q * 8;
      const short* Wh = W1h + (wave * 16 + l15) * KP + q * 8;
      const short* A0 = h0s + l15 * KP + q * 8;
      const short* A1 = h1s + l15 * KP + q * 8;
      #pragma unroll
      for (int kt = 0; kt < 8; ++kt) {
        s8v bf = *(const s8v*)(Wi + kt * 32);
        s8v a0 = *(const s8v*)(A0 + kt * 32);
        s8v a1 = *(const s8v*)(A0 + 16 * KP + kt * 32);
        acc0 = __builtin_amdgcn_mfma_f32_16x16x32_bf16(a0, bf, acc0, 0, 0, 0);
        acc1 = __builtin_amdgcn_mfma_f32_16x16x32_bf16(a1, bf, acc1, 0, 0, 0);
      }
      #pragma unroll
      for (int kt = 0; kt < 8; ++kt) {
        s8v bf = *(const s8v*)(Wh + kt * 32);
        s8v a0 = *(const s8v*)(A1 + kt * 32);
        s8v a1 = *(const s8v*)(A1 + 16 * KP + kt * 32);
        acc0 = __builtin_amdgcn_mfma_f32_16x16x32_bf16(a0, bf, acc0, 0, 0, 0);
        acc1 = __builtin_amdgcn_mfma_f32_16x16x32_bf16(a1, bf, acc1, 0, 0, 0);
      }
      float bia = bias1s[wave * 16 + l15];
      #pragma unroll
      for (int r = 0; r < 4; ++r) {
        int b0 = q * 4 + r;
        float v0 = acc0[r] + bia;
        float v1 = acc1[r] + bia;
        if (wave == 2) { v0 = tanh_f(v0); v1 = tanh_f(v1); }
        else           { v0 = sigm(v0);   v1 = sigm(v1);   }
        gbuf[(wave * 32 + b0     ) * 17 + l15] = v0;
        gbuf[(wave * 32 + b0 + 16) * 17 + l15] = v1;
      }
    }
    __syncthreads();
    if (s >= 1) {
      short* dst = h1g + (size_t)(((s - 1) & 1) * Bz + gbase) * Hz + sl * HU;
      for (int i = tid; i < BT * HU; i += 256) {
        int b = i >> 4, u = i & 15;
        float iv = gbuf[(     b) * 17 + u];
        float fv = gbuf[(32 + b) * 17 + u];
        float gv = gbuf[(64 + b) * 17 + u];
        float ov = gbuf[(96 + b) * 17 + u];
        float c = fv * c1[b * 17 + u] + iv * gv;
        c1[b * 17 + u] = c;
        dst[b * Hz + u] = f2bf(ov * tanh_f(c));
      }
    }

    // ---- group barrier: 16 blocks, monotonic counter, release/acquire agent scope ----
    __syncthreads();
    if (tid == 0) {
      __hip_atomic_fetch_add(bar, 1u, __ATOMIC_RELEASE, __HIP_MEMORY_SCOPE_AGENT);
      const unsigned tgt = (unsigned)(GS * (s + 1));
      while (__hip_atomic_load(bar, __ATOMIC_ACQUIRE, __HIP_MEMORY_SCOPE_AGENT) < tgt)
        __builtin_amdgcn_s_sleep(2);
    }
    __syncthreads();
  }

  // ---- final linear head: out = h1[T-1] @ w_lin^T + b_lin (slice-0 blocks) ----
  if (sl == 0) {
    const short* h1last = h1g + (size_t)(((Tz - 1) & 1) * Bz) * Hz;
    for (int i = tid; i < BT * Pz; i += 256) {
      int b = i / Pz, p = i - b * Pz;
      const short* hr = h1last + (size_t)(gbase + b) * Hz;
      float acc = b_lin[p];
      for (int k = 0; k < Hz; ++k)
        acc += bf2f(hr[k]) * w_lin[p * Hz + k];
      out[(gbase + b) * Pz + p] = acc;
    }
  }
}

extern "C" void kernel_launch(void* const* d_in, const int* in_sizes, int n_in,
                              void* d_out, int out_size, void* d_ws, size_t ws_size,
                              hipStream_t stream) {
  const float* x     = (const float*)d_in[0];
  const float* w_ih0 = (const float*)d_in[1];
  const float* w_hh0 = (const float*)d_in[2];
  const float* b_ih0 = (const float*)d_in[3];
  const float* b_hh0 = (const float*)d_in[4];
  const float* w_ih1 = (const float*)d_in[5];
  const float* w_hh1 = (const float*)d_in[6];
  const float* b_ih1 = (const float*)d_in[7];
  const float* b_hh1 = (const float*)d_in[8];
  const float* w_lin = (const float*)d_in[9];
  const float* b_lin = (const float*)d_in[10];
  float* out = (float*)d_out;

  unsigned char* ws = (unsigned char*)d_ws;
  unsigned* bars = (unsigned*)ws;                              // 16KB: barrier counters
  short* h0g = (short*)(ws + 16384);                           // [2][B][H] bf16
  short* h1g = (short*)(ws + 16384 + 2 * Bz * Hz * 2);         // [2][B][H] bf16
  size_t clear_bytes = 16384 + 2 * (size_t)(2 * Bz * Hz * 2);  // counters + both h buffers
  hipMemsetAsync(d_ws, 0, clear_bytes, stream);

  size_t lds_bytes = (size_t)(3 * 64 + 2 * 32) * KP * 2
                   + (size_t)(4 * 32 * 17 + 2 * 32 * 17 + 32 + 3 * 64) * 4;  // ~149KB
  hipFuncSetAttribute((const void*)lstm2,
                      hipFuncAttributeMaxDynamicSharedMemorySize, (int)lds_bytes);
  lstm2<<<GB * GS, 256, lds_bytes, stream>>>(x, w_ih0, w_hh0, b_ih0, b_hh0,
                                             w_ih1, w_hh1, b_ih1, b_hh1,
                                             w_lin, b_lin, out, bars, h0g, h1g);
}

// Round 2
// 1516.409 us; speedup vs baseline: 2.5859x; 2.5859x over previous
//
#include <hip/hip_runtime.h>

// Problem constants
constexpr int Bz = 512;   // batch
constexpr int Tz = 256;   // seq len
constexpr int Hz = 256;   // hidden
constexpr int Pz = 14;    // predict dim
constexpr int GB = 16;    // batch groups
constexpr int GS = 16;    // hidden slices per group
constexpr int BT = 32;    // batch per group (512/16)
constexpr int HU = 16;    // hidden units per slice (256/16)
constexpr int KP = 264;   // padded K stride in bf16 elems

typedef short s8v __attribute__((ext_vector_type(8)));
typedef float f4v __attribute__((ext_vector_type(4)));
typedef unsigned long long u64;

__device__ __forceinline__ short f2bf(float f) {
  unsigned u = __float_as_uint(f);
  u = (u + 0x7fffu + ((u >> 16) & 1u)) >> 16;   // RNE
  return (short)u;
}
__device__ __forceinline__ float bf2f(short s) {
  return __uint_as_float(((unsigned)(unsigned short)s) << 16);
}
__device__ __forceinline__ float sigm(float v) { return 1.0f / (1.0f + __expf(-v)); }
__device__ __forceinline__ float tanh_f(float v) { return 1.0f - 2.0f / (__expf(2.0f * v) + 1.0f); }

// All cross-block traffic uses RELAXED agent-scope atomics -> global_load/store sc1
// (per-access LLC coherence, NO buffer_inv / buffer_wbl2 cache maintenance).
// Ordering: __syncthreads drains vmcnt(0) per wave (completes sc1 write-through
// stores at LLC) before tid0 bumps the group counter; consumer loads are sc1
// (L2-bypass) so no acquire-invalidate is needed.
__global__ void __launch_bounds__(256, 1)
lstm2(const float* __restrict__ x,
      const float* __restrict__ w_ih0, const float* __restrict__ w_hh0,
      const float* __restrict__ b_ih0, const float* __restrict__ b_hh0,
      const float* __restrict__ w_ih1, const float* __restrict__ w_hh1,
      const float* __restrict__ b_ih1, const float* __restrict__ b_hh1,
      const float* __restrict__ w_lin, const float* __restrict__ b_lin,
      float* __restrict__ out,
      unsigned* __restrict__ bars,
      short* __restrict__ h0g, short* __restrict__ h1g)
{
  const int blk  = blockIdx.x;
  const int g    = blk >> 4;      // batch group
  const int sl   = blk & 15;      // hidden slice
  const int tid  = threadIdx.x;
  const int wave = tid >> 6;      // 4 waves: wave == gate type (i,f,g,o)
  const int lane = tid & 63;
  const int q    = lane >> 4;     // quad within wave
  const int l15  = lane & 15;
  const int gbase = g * BT;

  extern __shared__ char smem_raw[];
  short* W0   = (short*)smem_raw;          // [64][KP] W_hh0 slice (bf16)
  short* W1i  = W0  + 64 * KP;             // [64][KP] W_ih1 slice
  short* W1h  = W1i + 64 * KP;             // [64][KP] W_hh1 slice
  short* h0s  = W1h + 64 * KP;             // [32][KP] staged h0[t-1] (full H)
  short* h1s  = h0s + 32 * KP;             // [32][KP] staged h1[t-2] (full H)
  float* gbuf   = (float*)(h1s + 32 * KP); // [4][32][17] activated gates
  float* c0     = gbuf + 4 * 32 * 17;      // [32][17] cell state layer0 (slice-local)
  float* c1     = c0 + 32 * 17;            // [32][17] cell state layer1
  float* xs     = c1 + 32 * 17;            // [32] x[b][t]
  float* wih0s  = xs + 32;                 // [64] w_ih0 rows
  float* bias0s = wih0s + 64;              // [64] b_ih0+b_hh0
  float* bias1s = bias0s + 64;             // [64] b_ih1+b_hh1

  // ---- one-time: load weight slices into LDS (fp32 -> bf16) ----
  for (int i = tid; i < 64 * 256; i += 256) {
    int n = i >> 8, k = i & 255;
    int grow = (n >> 4) * Hz + sl * HU + (n & 15);  // gate*256 + global hidden unit
    W0 [n * KP + k] = f2bf(w_hh0[grow * Hz + k]);
    W1i[n * KP + k] = f2bf(w_ih1[grow * Hz + k]);
    W1h[n * KP + k] = f2bf(w_hh1[grow * Hz + k]);
  }
  if (tid < 64) {
    int n = tid;
    int grow = (n >> 4) * Hz + sl * HU + (n & 15);
    wih0s[n]  = w_ih0[grow];
    bias0s[n] = b_ih0[grow] + b_hh0[grow];
    bias1s[n] = b_ih1[grow] + b_hh1[grow];
  }
  for (int i = tid; i < 32 * 17; i += 256) { c0[i] = 0.0f; c1[i] = 0.0f; }
  __syncthreads();

  unsigned* bar = bars + (g << 6);   // 256B-separated counter per group

  for (int s = 0; s <= Tz; ++s) {
    // ---- stage h0[s-1] (buf (s+1)&1) and h1[s-2] (buf s&1) via sc1 loads ----
    {
      const u64* h0srcU = (const u64*)h0g + (size_t)(((s + 1) & 1) * Bz + gbase) * (Hz / 4);
      const u64* h1srcU = (const u64*)h1g + (size_t)(((s    ) & 1) * Bz + gbase) * (Hz / 4);
      for (int i = tid; i < BT * (Hz / 4); i += 256) {   // 2048 chunks of 8B
        int b = i >> 6, ch = i & 63;
        u64 v0 = __hip_atomic_load(h0srcU + (size_t)b * (Hz / 4) + ch,
                                   __ATOMIC_RELAXED, __HIP_MEMORY_SCOPE_AGENT);
        u64 v1 = __hip_atomic_load(h1srcU + (size_t)b * (Hz / 4) + ch,
                                   __ATOMIC_RELAXED, __HIP_MEMORY_SCOPE_AGENT);
        *(u64*)(h0s + b * KP + ch * 4) = v0;
        *(u64*)(h1s + b * KP + ch * 4) = v1;
      }
      if (tid < BT && s < Tz) xs[tid] = x[(gbase + tid) * Tz + s];
    }
    __syncthreads();

    // ---- layer 0, time t=s: gates = pre0 + h0_prev @ W0^T ----
    if (s < Tz) {
      f4v acc0 = {0.f, 0.f, 0.f, 0.f}, acc1 = {0.f, 0.f, 0.f, 0.f};
      const short* Wr = W0  + (wave * 16 + l15) * KP + q * 8;  // B-frag
      const short* Ar = h0s + l15 * KP + q * 8;                // A-frag
      #pragma unroll
      for (int kt = 0; kt < 8; ++kt) {
        s8v bf = *(const s8v*)(Wr + kt * 32);
        s8v a0 = *(const s8v*)(Ar + kt * 32);
        s8v a1 = *(const s8v*)(Ar + 16 * KP + kt * 32);
        acc0 = __builtin_amdgcn_mfma_f32_16x16x32_bf16(a0, bf, acc0, 0, 0, 0);
        acc1 = __builtin_amdgcn_mfma_f32_16x16x32_bf16(a1, bf, acc1, 0, 0, 0);
      }
      float wih = wih0s[wave * 16 + l15];
      float bia = bias0s[wave * 16 + l15];
      #pragma unroll
      for (int r = 0; r < 4; ++r) {
        int b0 = q * 4 + r;                        // D: row(m)=q*4+r, col(n)=l15
        float v0 = acc0[r] + xs[b0]      * wih + bia;
        float v1 = acc1[r] + xs[b0 + 16] * wih + bia;
        if (wave == 2) { v0 = tanh_f(v0); v1 = tanh_f(v1); }
        else           { v0 = sigm(v0);   v1 = sigm(v1);   }
        gbuf[(wave * 32 + b0     ) * 17 + l15] = v0;
        gbuf[(wave * 32 + b0 + 16) * 17 + l15] = v1;
      }
    }
    __syncthreads();
    if (s < Tz) {
      unsigned* dstU = (unsigned*)h0g + (size_t)((s & 1) * Bz + gbase) * (Hz / 2) + sl * (HU / 2);
      for (int i = tid; i < BT * HU / 2; i += 256) {   // 256: one per thread
        int b = i >> 3, p = i & 7, u = p * 2;
        float iv0 = gbuf[(     b) * 17 + u], iv1 = gbuf[(     b) * 17 + u + 1];
        float fv0 = gbuf[(32 + b) * 17 + u], fv1 = gbuf[(32 + b) * 17 + u + 1];
        float gv0 = gbuf[(64 + b) * 17 + u], gv1 = gbuf[(64 + b) * 17 + u + 1];
        float ov0 = gbuf[(96 + b) * 17 + u], ov1 = gbuf[(96 + b) * 17 + u + 1];
        float cA = fv0 * c0[b * 17 + u    ] + iv0 * gv0;
        float cB = fv1 * c0[b * 17 + u + 1] + iv1 * gv1;
        c0[b * 17 + u    ] = cA;
        c0[b * 17 + u + 1] = cB;
        unsigned pk = (unsigned)(unsigned short)f2bf(ov0 * tanh_f(cA))
                    | ((unsigned)(unsigned short)f2bf(ov1 * tanh_f(cB)) << 16);
        __hip_atomic_store(dstU + (size_t)b * (Hz / 2) + p, pk,
                           __ATOMIC_RELAXED, __HIP_MEMORY_SCOPE_AGENT);
      }
    }
    __syncthreads();   // gbuf reuse fence before layer1 epilogue

    // ---- layer 1, time t=s-1 ----
    if (s >= 1) {
      f4v acc0 = {0.f, 0.f, 0.f, 0.f}, acc1 = {0.f, 0.f, 0.f, 0.f};
      const short* Wi = W1i + (wave * 16 + l15) * KP + q * 8;
      const short* Wh = W1h + (wave * 16 + l15) * KP + q * 8;
      const short* A0 = h0s + l15 * KP + q * 8;
      const short* A1 = h1s + l15 * KP + q * 8;
      #pragma unroll
      for (int kt = 0; kt < 8; ++kt) {
        s8v bf = *(const s8v*)(Wi + kt * 32);
        s8v a0 = *(const s8v*)(A0 + kt * 32);
        s8v a1 = *(const s8v*)(A0 + 16 * KP + kt * 32);
        acc0 = __builtin_amdgcn_mfma_f32_16x16x32_bf16(a0, bf, acc0, 0, 0, 0);
        acc1 = __builtin_amdgcn_mfma_f32_16x16x32_bf16(a1, bf, acc1, 0, 0, 0);
      }
      #pragma unroll
      for (int kt = 0; kt < 8; ++kt) {
        s8v bf = *(const s8v*)(Wh + kt * 32);
        s8v a0 = *(const s8v*)(A1 + kt * 32);
        s8v a1 = *(const s8v*)(A1 + 16 * KP + kt * 32);
        acc0 = __builtin_amdgcn_mfma_f32_16x16x32_bf16(a0, bf, acc0, 0, 0, 0);
        acc1 = __builtin_amdgcn_mfma_f32_16x16x32_bf16(a1, bf, acc1, 0, 0, 0);
      }
      float bia = bias1s[wave * 16 + l15];
      #pragma unroll
      for (int r = 0; r < 4; ++r) {
        int b0 = q * 4 + r;
        float v0 = acc0[r] + bia;
        float v1 = acc1[r] + bia;
        if (wave == 2) { v0 = tanh_f(v0); v1 = tanh_f(v1); }
        else           { v0 = sigm(v0);   v1 = sigm(v1);   }
        gbuf[(wave * 32 + b0     ) * 17 + l15] = v0;
        gbuf[(wave * 32 + b0 + 16) * 17 + l15] = v1;
      }
    }
    __syncthreads();
    if (s >= 1) {
      unsigned* dstU = (unsigned*)h1g + (size_t)(((s - 1) & 1) * Bz + gbase) * (Hz / 2) + sl * (HU / 2);
      for (int i = tid; i < BT * HU / 2; i += 256) {
        int b = i >> 3, p = i & 7, u = p * 2;
        float iv0 = gbuf[(     b) * 17 + u], iv1 = gbuf[(     b) * 17 + u + 1];
        float fv0 = gbuf[(32 + b) * 17 + u], fv1 = gbuf[(32 + b) * 17 + u + 1];
        float gv0 = gbuf[(64 + b) * 17 + u], gv1 = gbuf[(64 + b) * 17 + u + 1];
        float ov0 = gbuf[(96 + b) * 17 + u], ov1 = gbuf[(96 + b) * 17 + u + 1];
        float cA = fv0 * c1[b * 17 + u    ] + iv0 * gv0;
        float cB = fv1 * c1[b * 17 + u + 1] + iv1 * gv1;
        c1[b * 17 + u    ] = cA;
        c1[b * 17 + u + 1] = cB;
        unsigned pk = (unsigned)(unsigned short)f2bf(ov0 * tanh_f(cA))
                    | ((unsigned)(unsigned short)f2bf(ov1 * tanh_f(cB)) << 16);
        __hip_atomic_store(dstU + (size_t)b * (Hz / 2) + p, pk,
                           __ATOMIC_RELAXED, __HIP_MEMORY_SCOPE_AGENT);
      }
    }

    // ---- group barrier: relaxed counter, no cache maintenance ----
    // __syncthreads drains vmcnt(0) per wave => sc1 stores visible at LLC
    // before tid0's counter bump (release). Consumer loads are sc1 (acquire-free).
    __syncthreads();
    if (tid == 0) {
      __hip_atomic_fetch_add(bar, 1u, __ATOMIC_RELAXED, __HIP_MEMORY_SCOPE_AGENT);
      const unsigned tgt = (unsigned)(GS * (s + 1));
      while (__hip_atomic_load(bar, __ATOMIC_RELAXED, __HIP_MEMORY_SCOPE_AGENT) < tgt)
        __builtin_amdgcn_s_sleep(1);
    }
    __syncthreads();
  }

  // ---- final linear head: out = h1[T-1] @ w_lin^T + b_lin (slice-0 blocks) ----
  if (sl == 0) {
    const u64* hU = (const u64*)h1g + (size_t)(((Tz - 1) & 1) * Bz + gbase) * (Hz / 4);
    for (int i = tid; i < BT * (Hz / 4); i += 256) {
      int b = i >> 6, ch = i & 63;
      u64 v = __hip_atomic_load(hU + (size_t)b * (Hz / 4) + ch,
                                __ATOMIC_RELAXED, __HIP_MEMORY_SCOPE_AGENT);
      *(u64*)(h0s + b * KP + ch * 4) = v;
    }
    __syncthreads();
    for (int i = tid; i < BT * Pz; i += 256) {
      int b = i / Pz, p = i - b * Pz;
      float acc = b_lin[p];
      for (int k = 0; k < Hz; ++k)
        acc += bf2f(h0s[b * KP + k]) * w_lin[p * Hz + k];
      out[(gbase + b) * Pz + p] = acc;
    }
  }
}

extern "C" void kernel_launch(void* const* d_in, const int* in_sizes, int n_in,
                              void* d_out, int out_size, void* d_ws, size_t ws_size,
                              hipStream_t stream) {
  const float* x     = (const float*)d_in[0];
  const float* w_ih0 = (const float*)d_in[1];
  const float* w_hh0 = (const float*)d_in[2];
  const float* b_ih0 = (const float*)d_in[3];
  const float* b_hh0 = (const float*)d_in[4];
  const float* w_ih1 = (const float*)d_in[5];
  const float* w_hh1 = (const float*)d_in[6];
  const float* b_ih1 = (const float*)d_in[7];
  const float* b_hh1 = (const float*)d_in[8];
  const float* w_lin = (const float*)d_in[9];
  const float* b_lin = (const float*)d_in[10];
  float* out = (float*)d_out;

  unsigned char* ws = (unsigned char*)d_ws;
  unsigned* bars = (unsigned*)ws;                              // 16KB: barrier counters
  short* h0g = (short*)(ws + 16384);                           // [2][B][H] bf16
  short* h1g = (short*)(ws + 16384 + 2 * Bz * Hz * 2);         // [2][B][H] bf16
  size_t clear_bytes = 16384 + 2 * (size_t)(2 * Bz * Hz * 2);
  hipMemsetAsync(d_ws, 0, clear_bytes, stream);

  size_t lds_bytes = (size_t)(3 * 64 + 2 * 32) * KP * 2
                   + (size_t)(4 * 32 * 17 + 2 * 32 * 17 + 32 + 3 * 64) * 4;  // ~149KB
  hipFuncSetAttribute((const void*)lstm2,
                      hipFuncAttributeMaxDynamicSharedMemorySize, (int)lds_bytes);
  lstm2<<<GB * GS, 256, lds_bytes, stream>>>(x, w_ih0, w_hh0, b_ih0, b_hh0,
                                             w_ih1, w_hh1, b_ih1, b_hh1,
                                             w_lin, b_lin, out, bars, h0g, h1g);
}

// Round 3
// 1016.730 us; speedup vs baseline: 3.8567x; 1.4915x over previous
//
#include <hip/hip_runtime.h>

// Problem constants
constexpr int Bz = 512;   // batch
constexpr int Tz = 256;   // seq len
constexpr int Hz = 256;   // hidden
constexpr int Pz = 14;    // predict dim
constexpr int GB = 16;    // batch groups
constexpr int GS = 16;    // hidden slices per group
constexpr int BT = 32;    // batch per group (512/16)
constexpr int HU = 16;    // hidden units per slice (256/16)
constexpr int KP = 264;   // padded K stride in bf16 elems (breaks LDS bank aliasing)

typedef short s8v __attribute__((ext_vector_type(8)));
typedef float f4v __attribute__((ext_vector_type(4)));
typedef unsigned long long u64;

__device__ __forceinline__ short f2bf(float f) {
  unsigned u = __float_as_uint(f);
  u = (u + 0x7fffu + ((u >> 16) & 1u)) >> 16;   // RNE
  return (short)u;
}
__device__ __forceinline__ float bf2f(short s) {
  return __uint_as_float(((unsigned)(unsigned short)s) << 16);
}
__device__ __forceinline__ float sigm(float v) { return 1.0f / (1.0f + __expf(-v)); }
__device__ __forceinline__ float tanh_f(float v) { return 1.0f - 2.0f / (__expf(2.0f * v) + 1.0f); }

// Layout trick: C = W @ h^T with LDS weight rows ordered unit*4+gate. MFMA C
// layout (col=lane&15=batch, row=q*4+reg) then gives each lane the i,f,g,o
// gates of ONE (unit,batch) pair in its 4 acc regs -> cell update fully
// in-register, c-state in VGPRs, no gate LDS round-trip, L0+L1 MFMAs fused
// into a single phase (both depend only on staged h from previous steps).
__global__ void __launch_bounds__(256, 1)
lstm2(const float* __restrict__ x,
      const float* __restrict__ w_ih0, const float* __restrict__ w_hh0,
      const float* __restrict__ b_ih0, const float* __restrict__ b_hh0,
      const float* __restrict__ w_ih1, const float* __restrict__ w_hh1,
      const float* __restrict__ b_ih1, const float* __restrict__ b_hh1,
      const float* __restrict__ w_lin, const float* __restrict__ b_lin,
      float* __restrict__ out,
      unsigned* __restrict__ bars,
      short* __restrict__ h0g, short* __restrict__ h1g)
{
  const int blk  = blockIdx.x;
  const int g    = blk >> 4;      // batch group
  const int sl   = blk & 15;      // hidden slice
  const int tid  = threadIdx.x;
  const int wave = tid >> 6;
  const int lane = tid & 63;
  const int q    = lane >> 4;
  const int l15  = lane & 15;
  const int gbase = g * BT;

  extern __shared__ char smem_raw[];
  short* W0  = (short*)smem_raw;     // [64][KP] W_hh0 slice, row = unit*4+gate
  short* W1i = W0  + 64 * KP;        // [64][KP] W_ih1 slice
  short* W1h = W1i + 64 * KP;        // [64][KP] W_hh1 slice
  short* h0s = W1h + 64 * KP;        // [32][KP] staged h0[s-1] (full H)
  short* h1s = h0s + 32 * KP;        // [32][KP] staged h1[s-2] (full H)
  short* hp0 = h1s + 32 * KP;        // [32][16] packed h0 out (batch-major)
  short* hp1 = hp0 + 32 * 16;        // [32][16] packed h1 out
  float* xs  = (float*)(hp1 + 32 * 16);  // [32]

  // ---- one-time: weight slices -> LDS (fp32 -> bf16), row rr = unit*4+gate ----
  for (int i = tid; i < 64 * 256; i += 256) {
    int rr = i >> 8, k = i & 255;
    int grow = (rr & 3) * Hz + sl * HU + (rr >> 2);
    W0 [rr * KP + k] = f2bf(w_hh0[grow * Hz + k]);
    W1i[rr * KP + k] = f2bf(w_ih1[grow * Hz + k]);
    W1h[rr * KP + k] = f2bf(w_hh1[grow * Hz + k]);
  }
  // per-thread constants: this lane owns unit = wave*4+q, gates r=0..3
  const int myunit = wave * 4 + q;
  float wihR[4], b0R[4], b1R[4];
  #pragma unroll
  for (int r = 0; r < 4; ++r) {
    int grow = r * Hz + sl * HU + myunit;
    wihR[r] = w_ih0[grow];
    b0R[r]  = b_ih0[grow] + b_hh0[grow];
    b1R[r]  = b_ih1[grow] + b_hh1[grow];
  }
  float c0a = 0.f, c0b = 0.f, c1a = 0.f, c1b = 0.f;  // cell state in VGPRs
  __syncthreads();

  unsigned* bar = bars + (g << 6);

  for (int s = 0; s <= Tz; ++s) {
    // ---- stage h0[s-1] (buf (s+1)&1) and h1[s-2] (buf s&1): regs first ----
    {
      const u64* h0src = (const u64*)h0g + (size_t)(((s + 1) & 1) * Bz + gbase) * (Hz / 4);
      const u64* h1src = (const u64*)h1g + (size_t)(((s    ) & 1) * Bz + gbase) * (Hz / 4);
      u64 r0[8], r1[8];
      #pragma unroll
      for (int k2 = 0; k2 < 8; ++k2) {
        int b = wave + k2 * 4;
        r0[k2] = __hip_atomic_load(h0src + (size_t)b * (Hz / 4) + lane,
                                   __ATOMIC_RELAXED, __HIP_MEMORY_SCOPE_AGENT);
        r1[k2] = __hip_atomic_load(h1src + (size_t)b * (Hz / 4) + lane,
                                   __ATOMIC_RELAXED, __HIP_MEMORY_SCOPE_AGENT);
      }
      #pragma unroll
      for (int k2 = 0; k2 < 8; ++k2) {
        int b = wave + k2 * 4;
        *(u64*)(h0s + b * KP + lane * 4) = r0[k2];
        *(u64*)(h1s + b * KP + lane * 4) = r1[k2];
      }
      if (tid < BT && s < Tz) xs[tid] = x[(gbase + tid) * Tz + s];
    }
    __syncthreads();

    // ---- fused MFMA phase: L0 (16) + L1 (32), all from staged LDS ----
    f4v aL0a = {0.f,0.f,0.f,0.f}, aL0b = {0.f,0.f,0.f,0.f};
    f4v aL1a = {0.f,0.f,0.f,0.f}, aL1b = {0.f,0.f,0.f,0.f};
    const short* Wr0 = W0  + (wave * 16 + l15) * KP + q * 8;  // A: W row m=wave*16+l15
    const short* Wri = W1i + (wave * 16 + l15) * KP + q * 8;
    const short* Wrh = W1h + (wave * 16 + l15) * KP + q * 8;
    const short* H0f = h0s + l15 * KP + q * 8;                // B: h col n=batch l15
    const short* H1f = h1s + l15 * KP + q * 8;
    if (s < Tz) {
      #pragma unroll
      for (int kt = 0; kt < 8; ++kt) {
        s8v wv = *(const s8v*)(Wr0 + kt * 32);
        s8v ha = *(const s8v*)(H0f + kt * 32);
        s8v hb = *(const s8v*)(H0f + 16 * KP + kt * 32);
        aL0a = __builtin_amdgcn_mfma_f32_16x16x32_bf16(wv, ha, aL0a, 0, 0, 0);
        aL0b = __builtin_amdgcn_mfma_f32_16x16x32_bf16(wv, hb, aL0b, 0, 0, 0);
      }
    }
    if (s >= 1) {
      #pragma unroll
      for (int kt = 0; kt < 8; ++kt) {
        s8v wi  = *(const s8v*)(Wri + kt * 32);
        s8v wh  = *(const s8v*)(Wrh + kt * 32);
        s8v h0a = *(const s8v*)(H0f + kt * 32);
        s8v h0b = *(const s8v*)(H0f + 16 * KP + kt * 32);
        s8v h1a = *(const s8v*)(H1f + kt * 32);
        s8v h1b = *(const s8v*)(H1f + 16 * KP + kt * 32);
        aL1a = __builtin_amdgcn_mfma_f32_16x16x32_bf16(wi, h0a, aL1a, 0, 0, 0);
        aL1b = __builtin_amdgcn_mfma_f32_16x16x32_bf16(wi, h0b, aL1b, 0, 0, 0);
        aL1a = __builtin_amdgcn_mfma_f32_16x16x32_bf16(wh, h1a, aL1a, 0, 0, 0);
        aL1b = __builtin_amdgcn_mfma_f32_16x16x32_bf16(wh, h1b, aL1b, 0, 0, 0);
      }
    }

    // ---- in-register epilogues: acc[r] = gate r of (myunit, batch l15 / 16+l15) ----
    if (s < Tz) {
      float xa = xs[l15], xb = xs[16 + l15];
      float ia = sigm  (aL0a[0] + xa * wihR[0] + b0R[0]);
      float fa = sigm  (aL0a[1] + xa * wihR[1] + b0R[1]);
      float ga = tanh_f(aL0a[2] + xa * wihR[2] + b0R[2]);
      float oa = sigm  (aL0a[3] + xa * wihR[3] + b0R[3]);
      c0a = fa * c0a + ia * ga;
      hp0[l15 * HU + myunit] = f2bf(oa * tanh_f(c0a));
      float ib = sigm  (aL0b[0] + xb * wihR[0] + b0R[0]);
      float fb = sigm  (aL0b[1] + xb * wihR[1] + b0R[1]);
      float gb = tanh_f(aL0b[2] + xb * wihR[2] + b0R[2]);
      float ob = sigm  (aL0b[3] + xb * wihR[3] + b0R[3]);
      c0b = fb * c0b + ib * gb;
      hp0[(16 + l15) * HU + myunit] = f2bf(ob * tanh_f(c0b));
    }
    if (s >= 1) {
      float ia = sigm  (aL1a[0] + b1R[0]);
      float fa = sigm  (aL1a[1] + b1R[1]);
      float ga = tanh_f(aL1a[2] + b1R[2]);
      float oa = sigm  (aL1a[3] + b1R[3]);
      c1a = fa * c1a + ia * ga;
      hp1[l15 * HU + myunit] = f2bf(oa * tanh_f(c1a));
      float ib = sigm  (aL1b[0] + b1R[0]);
      float fb = sigm  (aL1b[1] + b1R[1]);
      float gb = tanh_f(aL1b[2] + b1R[2]);
      float ob = sigm  (aL1b[3] + b1R[3]);
      c1b = fb * c1b + ib * gb;
      hp1[(16 + l15) * HU + myunit] = f2bf(ob * tanh_f(c1b));
    }
    __syncthreads();

    // ---- packed sc1 stores: 32B (4x u64) per batch per slice ----
    if (s < Tz && tid < 128) {
      int b = tid >> 2, chunk = tid & 3;
      u64 v = *(const u64*)(hp0 + b * HU + chunk * 4);
      __hip_atomic_store((u64*)h0g + (size_t)((s & 1) * Bz + gbase + b) * (Hz / 4) + sl * 4 + chunk,
                         v, __ATOMIC_RELAXED, __HIP_MEMORY_SCOPE_AGENT);
    }
    if (s >= 1 && tid >= 128) {
      int t2 = tid - 128;
      int b = t2 >> 2, chunk = t2 & 3;
      u64 v = *(const u64*)(hp1 + b * HU + chunk * 4);
      __hip_atomic_store((u64*)h1g + (size_t)(((s - 1) & 1) * Bz + gbase + b) * (Hz / 4) + sl * 4 + chunk,
                         v, __ATOMIC_RELAXED, __HIP_MEMORY_SCOPE_AGENT);
    }

    // ---- group barrier (vmcnt drained per-wave at syncthreads before add) ----
    __syncthreads();
    if (tid == 0) {
      __hip_atomic_fetch_add(bar, 1u, __ATOMIC_RELAXED, __HIP_MEMORY_SCOPE_AGENT);
      const unsigned tgt = (unsigned)(GS * (s + 1));
      while (__hip_atomic_load(bar, __ATOMIC_RELAXED, __HIP_MEMORY_SCOPE_AGENT) < tgt)
        __builtin_amdgcn_s_sleep(1);
    }
    __syncthreads();
  }

  // ---- final linear head: out = h1[T-1] @ w_lin^T + b_lin (slice-0 blocks) ----
  if (sl == 0) {
    const u64* hU = (const u64*)h1g + (size_t)(((Tz - 1) & 1) * Bz + gbase) * (Hz / 4);
    for (int i = tid; i < BT * (Hz / 4); i += 256) {
      int b = i >> 6, ch = i & 63;
      u64 v = __hip_atomic_load(hU + (size_t)b * (Hz / 4) + ch,
                                __ATOMIC_RELAXED, __HIP_MEMORY_SCOPE_AGENT);
      *(u64*)(h0s + b * KP + ch * 4) = v;
    }
    __syncthreads();
    for (int i = tid; i < BT * Pz; i += 256) {
      int b = i / Pz, p = i - b * Pz;
      float acc = b_lin[p];
      for (int k = 0; k < Hz; ++k)
        acc += bf2f(h0s[b * KP + k]) * w_lin[p * Hz + k];
      out[(gbase + b) * Pz + p] = acc;
    }
  }
}

extern "C" void kernel_launch(void* const* d_in, const int* in_sizes, int n_in,
                              void* d_out, int out_size, void* d_ws, size_t ws_size,
                              hipStream_t stream) {
  const float* x     = (const float*)d_in[0];
  const float* w_ih0 = (const float*)d_in[1];
  const float* w_hh0 = (const float*)d_in[2];
  const float* b_ih0 = (const float*)d_in[3];
  const float* b_hh0 = (const float*)d_in[4];
  const float* w_ih1 = (const float*)d_in[5];
  const float* w_hh1 = (const float*)d_in[6];
  const float* b_ih1 = (const float*)d_in[7];
  const float* b_hh1 = (const float*)d_in[8];
  const float* w_lin = (const float*)d_in[9];
  const float* b_lin = (const float*)d_in[10];
  float* out = (float*)d_out;

  unsigned char* ws = (unsigned char*)d_ws;
  unsigned* bars = (unsigned*)ws;                              // 16KB: barrier counters
  short* h0g = (short*)(ws + 16384);                           // [2][B][H] bf16
  short* h1g = (short*)(ws + 16384 + 2 * Bz * Hz * 2);         // [2][B][H] bf16
  size_t clear_bytes = 16384 + 2 * (size_t)(2 * Bz * Hz * 2);
  hipMemsetAsync(d_ws, 0, clear_bytes, stream);

  size_t lds_bytes = (size_t)(3 * 64 + 2 * 32) * KP * 2   // weights + staging
                   + (size_t)(2 * 32 * 16) * 2            // hp0/hp1
                   + (size_t)32 * 4;                      // xs
  hipFuncSetAttribute((const void*)lstm2,
                      hipFuncAttributeMaxDynamicSharedMemorySize, (int)lds_bytes);
  lstm2<<<GB * GS, 256, lds_bytes, stream>>>(x, w_ih0, w_hh0, b_ih0, b_hh0,
                                             w_ih1, w_hh1, b_ih1, b_hh1,
                                             w_lin, b_lin, out, bars, h0g, h1g);
}